// Round 4
// baseline (171.520 us; speedup 1.0000x reference)
//
#include <hip/hip_runtime.h>
#include <math.h>

#define EPS 1e-6f
#define N 64          // INPUT_SIZE == NUM_LEAVES
#define NLAYERS 63
#define SINK_ITERS 20
#define LOG2E 1.4426950408889634f
#define LN2   0.6931471805599453f

struct LP { float w0, w1, e0, e1, cl, cg, a; int mode; };  // 32 B

// ---------------------------------------------------------------------------
// Kernel 1: Sinkhorn normalization (64x64, 20 iters) + per-layer param precompute.
// One block, 1024 threads: 64 groups of 16 lanes, 4 elements per thread.
// ---------------------------------------------------------------------------
__global__ __launch_bounds__(1024) void sinkhorn_kernel(
    const float* __restrict__ logits,
    const float* __restrict__ weights,
    const float* __restrict__ biases,
    float* __restrict__ P,       // [64][64] natural layout: P[k][j]
    LP* __restrict__ layers) {
  __shared__ float L[N][N + 1];  // +1 pad: conflict-free column access
  const int tid = threadIdx.x;
  const int g  = tid >> 4;       // group 0..63 (row in row-pass, col in col-pass)
  const int c0 = (tid & 15) * 4; // 4 consecutive elements per thread

  {
    float4 v = *(const float4*)(logits + g * N + c0);
    L[g][c0+0] = v.x; L[g][c0+1] = v.y; L[g][c0+2] = v.z; L[g][c0+3] = v.w;
  }
  __syncthreads();

  for (int it = 0; it < SINK_ITERS; ++it) {
    // ---- row pass: subtract logsumexp over axis=1 from row g ----
    {
      float v0 = L[g][c0+0], v1 = L[g][c0+1], v2 = L[g][c0+2], v3 = L[g][c0+3];
      float s = exp2f(v0 * LOG2E) + exp2f(v1 * LOG2E)
              + exp2f(v2 * LOG2E) + exp2f(v3 * LOG2E);
      #pragma unroll
      for (int mk = 1; mk < 16; mk <<= 1) s += __shfl_xor(s, mk, 16);
      float lse = LN2 * log2f(s);
      L[g][c0+0] = v0 - lse; L[g][c0+1] = v1 - lse;
      L[g][c0+2] = v2 - lse; L[g][c0+3] = v3 - lse;
    }
    __syncthreads();
    // ---- col pass: subtract logsumexp over axis=0 from col g ----
    {
      float v0 = L[c0+0][g], v1 = L[c0+1][g], v2 = L[c0+2][g], v3 = L[c0+3][g];
      float s = exp2f(v0 * LOG2E) + exp2f(v1 * LOG2E)
              + exp2f(v2 * LOG2E) + exp2f(v3 * LOG2E);
      #pragma unroll
      for (int mk = 1; mk < 16; mk <<= 1) s += __shfl_xor(s, mk, 16);
      float lse = LN2 * log2f(s);
      L[c0+0][g] = v0 - lse; L[c0+1][g] = v1 - lse;
      L[c0+2][g] = v2 - lse; L[c0+3][g] = v3 - lse;
    }
    __syncthreads();
  }

  // P = exp(L), natural [k][j] layout.
  #pragma unroll
  for (int i = 0; i < 4; ++i)
    P[g * N + c0 + i] = exp2f(L[g][c0 + i] * LOG2E);

  // Per-layer scan constants (a = bias in [0,1): |a-2|<eps never fires).
  if (tid < NLAYERS) {
    float w0 = weights[tid];
    float w1 = 1.0f - w0;
    float a  = biases[tid];
    LP p; p.w0 = w0; p.w1 = w1; p.a = a;
    p.e0 = 0.f; p.e1 = 0.f; p.cl = 0.f; p.cg = 0.f;
    if (fabsf(a - 0.5f) < EPS) {
      p.mode = 0;                       // pure linear
    } else {
      float ae;                         // effective 'a' handed to F_base
      if (a < 0.5f) {                   // De Morgan reflection branch
        p.mode = 2;
        ae = fminf(fmaxf(1.0f - a, -1.0f + EPS), 2.0f - EPS);
      } else {
        p.mode = 1;
        ae = a;
      }
      float pp = sqrtf(3.0f / fmaxf(2.0f - ae, EPS)) - 1.0f;
      if (ae >= 0.75f) { p.cl = 0.0f;            p.cg = 1.0f; }
      else             { p.cl = 3.0f - 4.0f*ae;  p.cg = 4.0f*ae - 2.0f; }
      p.e0 = 2.0f * w0 * pp;            // g = exp2(e0*log2(x) + e1*log2(y))
      p.e1 = 2.0f * w1 * pp;
    }
    layers[tid] = p;
  }
}

// ---------------------------------------------------------------------------
// F step (wave-uniform branch; lp comes from uniform scalar loads).
// ---------------------------------------------------------------------------
__device__ __forceinline__ float F_step(float state, float leaf, const LP lp) {
  float xx = fminf(fmaxf(state, EPS), 1.0f - EPS);
  float yy = fminf(fmaxf(leaf,  EPS), 1.0f - EPS);
  float r;
  if (lp.mode == 0) {
    r = lp.w0 * xx + lp.w1 * yy;
  } else {
    if (lp.mode == 2) { xx = 1.0f - xx; yy = 1.0f - yy; }
    float lin = lp.w0 * xx + lp.w1 * yy;
    float g   = exp2f(lp.e0 * log2f(xx) + lp.e1 * log2f(yy));
    r = lp.cl * lin + lp.cg * g;
    if (lp.mode == 2) r = 1.0f - r;
  }
  return (r != r) ? lp.a : r;  // NaN fallback to bias
}

// ---------------------------------------------------------------------------
// Kernel 2: fused (x @ P) + tree scan, TWO HALF-PASSES of 32 accumulators.
// Halved live-register set -> pure VGPR allocation (~60 regs), 6 waves/SIMD.
// x re-read in pass B hits L1/L2 (32 KB per 128-thread block).
// ---------------------------------------------------------------------------
__global__ __launch_bounds__(128, 6) void scan_kernel(
    const float* __restrict__ x,
    const float* __restrict__ P,
    const LP* __restrict__ layers,
    float* __restrict__ out) {
  const int b = blockIdx.x * 128 + threadIdx.x;
  const float4* xp = (const float4*)(x + ((size_t)b << 6));

  float st;
  // ---- pass A: leaves 0..31 ----
  {
    float acc[32];
    #pragma unroll
    for (int j = 0; j < 32; ++j) acc[j] = 0.0f;
    for (int k4 = 0; k4 < 16; ++k4) {
      float4 xk = xp[k4];
      const float* __restrict__ pr = P + (k4 << 8);  // rows 4k4..4k4+3
      #pragma unroll
      for (int j = 0; j < 32; ++j) acc[j] = fmaf(xk.x, pr[j],       acc[j]);
      #pragma unroll
      for (int j = 0; j < 32; ++j) acc[j] = fmaf(xk.y, pr[N + j],   acc[j]);
      #pragma unroll
      for (int j = 0; j < 32; ++j) acc[j] = fmaf(xk.z, pr[2*N + j], acc[j]);
      #pragma unroll
      for (int j = 0; j < 32; ++j) acc[j] = fmaf(xk.w, pr[3*N + j], acc[j]);
    }
    st = acc[0];
    #pragma unroll
    for (int j = 1; j < 32; ++j) st = F_step(st, acc[j], layers[j - 1]);
  }
  // ---- pass B: leaves 32..63 ----
  {
    float acc[32];
    #pragma unroll
    for (int j = 0; j < 32; ++j) acc[j] = 0.0f;
    for (int k4 = 0; k4 < 16; ++k4) {
      float4 xk = xp[k4];
      const float* __restrict__ pr = P + (k4 << 8) + 32;
      #pragma unroll
      for (int j = 0; j < 32; ++j) acc[j] = fmaf(xk.x, pr[j],       acc[j]);
      #pragma unroll
      for (int j = 0; j < 32; ++j) acc[j] = fmaf(xk.y, pr[N + j],   acc[j]);
      #pragma unroll
      for (int j = 0; j < 32; ++j) acc[j] = fmaf(xk.z, pr[2*N + j], acc[j]);
      #pragma unroll
      for (int j = 0; j < 32; ++j) acc[j] = fmaf(xk.w, pr[3*N + j], acc[j]);
    }
    #pragma unroll
    for (int j = 0; j < 32; ++j) st = F_step(st, acc[j], layers[31 + j]);
  }
  out[b] = st;
}

// ---------------------------------------------------------------------------
extern "C" void kernel_launch(void* const* d_in, const int* in_sizes, int n_in,
                              void* d_out, int out_size, void* d_ws, size_t ws_size,
                              hipStream_t stream) {
  const float* x       = (const float*)d_in[0];
  const float* logits  = (const float*)d_in[1];
  const float* weights = (const float*)d_in[2];
  const float* biases  = (const float*)d_in[3];
  float* out = (float*)d_out;

  float* P   = (float*)d_ws;                                  // 16 KB
  LP* layers = (LP*)((char*)d_ws + N * N * sizeof(float));    // 63 * 32 B

  const int batch = out_size;  // 262144

  hipLaunchKernelGGL(sinkhorn_kernel, dim3(1), dim3(1024), 0, stream,
                     logits, weights, biases, P, layers);
  hipLaunchKernelGGL(scan_kernel, dim3(batch / 128), dim3(128), 0, stream,
                     x, P, layers, out);
}

// Round 5
// 152.369 us; speedup vs baseline: 1.1257x; 1.1257x over previous
//
#include <hip/hip_runtime.h>
#include <math.h>

#define EPS 1e-6f
#define N 64          // INPUT_SIZE == NUM_LEAVES
#define NLAYERS 63
#define SINK_ITERS 20
#define LOG2E 1.4426950408889634f

// Constant-address-space float: uniform loads compile to s_load_* (scalar
// pipe, SGPR dest) -> inner-loop fmac takes P as an SGPR operand, no VMEM.
typedef __attribute__((address_space(4))) const float c4float;

// ---------------------------------------------------------------------------
// Kernel 1: Sinkhorn via scaling vectors, SINGLE WAVE.
// P = diag(u) * K * diag(v), K = exp(logits). Log-space reference iteration
// (row-lse then col-lse) is algebraically: u = 1/(K v); v = 1/(K^T u).
// Lane l holds row l of K and row l of K^T in registers; u/v are exchanged
// through 64-float LDS slots (single wave -> barriers are ~free).
// ---------------------------------------------------------------------------
__global__ __launch_bounds__(64) void sinkhorn_kernel(
    const float* __restrict__ logits,
    const float* __restrict__ weights,
    const float* __restrict__ biases,
    float* __restrict__ P,        // [64][64]
    float* __restrict__ layers) { // [63][8]: w0,w1,e0,e1,cl,cg,a,mode
  __shared__ float T[64 * 65 + 128];  // padded transpose area + u/v slots
  const int l = threadIdx.x;          // lane 0..63

  // K row l = exp(logits[l][:])
  float K[64];
  {
    const float4* lr = (const float4*)(logits + (l << 6));
    #pragma unroll
    for (int q = 0; q < 16; ++q) {
      float4 t = lr[q];
      K[4*q+0] = exp2f(t.x * LOG2E);
      K[4*q+1] = exp2f(t.y * LOG2E);
      K[4*q+2] = exp2f(t.z * LOG2E);
      K[4*q+3] = exp2f(t.w * LOG2E);
    }
  }
  // Transpose through padded LDS (row stride 65 dwords -> conflict-light).
  #pragma unroll
  for (int j = 0; j < 64; ++j) T[l * 65 + j] = K[j];
  __syncthreads();
  float KT[64];
  #pragma unroll
  for (int k = 0; k < 64; ++k) KT[k] = T[k * 65 + l];
  __syncthreads();

  float* Uv = &T[64 * 65];
  float* Vv = &T[64 * 65 + 64];
  Vv[l] = 1.0f;                 // v_0 = 1
  __syncthreads();

  float u = 1.0f;
  for (int it = 0; it < SINK_ITERS; ++it) {
    // row pass: u = 1 / (K v)
    float r = 0.f;
    #pragma unroll
    for (int j = 0; j < 64; ++j) r = fmaf(K[j], Vv[j], r);
    u = 1.0f / r;
    __syncthreads();            // WAR on Uv from previous iteration's reads
    Uv[l] = u;
    __syncthreads();
    // col pass: v = 1 / (K^T u)
    float c = 0.f;
    #pragma unroll
    for (int k = 0; k < 64; ++k) c = fmaf(KT[k], Uv[k], c);
    float v = 1.0f / c;
    __syncthreads();            // WAR on Vv (r-loop above reads it)
    Vv[l] = v;
    __syncthreads();
  }

  // P[l][j] = u[l] * K[l][j] * v[j]
  {
    float4* Pr = (float4*)(P + (l << 6));
    #pragma unroll
    for (int q = 0; q < 16; ++q) {
      float4 o;
      o.x = u * K[4*q+0] * Vv[4*q+0];
      o.y = u * K[4*q+1] * Vv[4*q+1];
      o.z = u * K[4*q+2] * Vv[4*q+2];
      o.w = u * K[4*q+3] * Vv[4*q+3];
      Pr[q] = o;
    }
  }

  // Per-layer scan constants (a = bias in [0,1): the |a-2|<eps rule never
  // fires; a_ref = 1-a lands in (0.5,1]).
  if (l < NLAYERS) {
    float w0 = weights[l];
    float w1 = 1.0f - w0;
    float a  = biases[l];
    float e0 = 0.f, e1 = 0.f, cl = 0.f, cg = 0.f, mode;
    if (fabsf(a - 0.5f) < EPS) {
      mode = 0.0f;                       // pure linear
    } else {
      float ae;                          // effective 'a' for F_base
      if (a < 0.5f) {                    // De Morgan reflection
        mode = 2.0f;
        ae = fminf(fmaxf(1.0f - a, -1.0f + EPS), 2.0f - EPS);
      } else {
        mode = 1.0f;
        ae = a;
      }
      float pp = sqrtf(3.0f / fmaxf(2.0f - ae, EPS)) - 1.0f;
      if (ae >= 0.75f) { cl = 0.0f;            cg = 1.0f; }
      else             { cl = 3.0f - 4.0f*ae;  cg = 4.0f*ae - 2.0f; }
      e0 = 2.0f * w0 * pp;               // g = exp2(e0*log2(x) + e1*log2(y))
      e1 = 2.0f * w1 * pp;
    }
    float* Lr = layers + l * 8;
    Lr[0] = w0; Lr[1] = w1; Lr[2] = e0; Lr[3] = e1;
    Lr[4] = cl; Lr[5] = cg; Lr[6] = a;  Lr[7] = mode;
  }
}

// ---------------------------------------------------------------------------
// Kernel 2: fused (x @ P) + tree scan. One thread per batch element,
// 64 accumulators; P and layer params delivered via the SCALAR pipe
// (address_space(4) -> s_load), so the k-loop is pure v_fmac vdst, sP, vx.
// ---------------------------------------------------------------------------
__global__ __launch_bounds__(256) void scan_kernel(
    const float* __restrict__ x,
    const float* __restrict__ P,
    const float* __restrict__ layers,
    float* __restrict__ out) {
  const int b = blockIdx.x * 256 + threadIdx.x;
  const float4* xp = (const float4*)(x + ((size_t)b << 6));
  c4float* Pc = (c4float*)(unsigned long long)P;
  c4float* Lc = (c4float*)(unsigned long long)layers;

  float acc[N];
  #pragma unroll
  for (int j = 0; j < N; ++j) acc[j] = 0.0f;

  // Rolled k4 loop (icache): body = 1 float4 VMEM load + 256 scalar-operand
  // fmacs; P addresses are uniform (base SGPR + const offsets) -> s_load.
  for (int k4 = 0; k4 < 16; ++k4) {
    float4 xk = xp[k4];
    const int base = k4 << 8;
    #pragma unroll
    for (int j = 0; j < N; ++j) acc[j] = fmaf(xk.x, Pc[base + j],       acc[j]);
    #pragma unroll
    for (int j = 0; j < N; ++j) acc[j] = fmaf(xk.y, Pc[base + N + j],   acc[j]);
    #pragma unroll
    for (int j = 0; j < N; ++j) acc[j] = fmaf(xk.z, Pc[base + 2*N + j], acc[j]);
    #pragma unroll
    for (int j = 0; j < N; ++j) acc[j] = fmaf(xk.w, Pc[base + 3*N + j], acc[j]);
  }

  // Left-leaning tree scan; all layer params are scalar loads, branches
  // wave-uniform.
  float st = acc[0];
  #pragma unroll
  for (int j = 1; j < N; ++j) {
    const int lb = (j - 1) * 8;
    float w0 = Lc[lb+0], w1 = Lc[lb+1], e0 = Lc[lb+2], e1 = Lc[lb+3];
    float cl = Lc[lb+4], cg = Lc[lb+5], av = Lc[lb+6], mf = Lc[lb+7];
    float xx = fminf(fmaxf(st,     EPS), 1.0f - EPS);
    float yy = fminf(fmaxf(acc[j], EPS), 1.0f - EPS);
    float r;
    if (mf < 0.5f) {
      r = w0 * xx + w1 * yy;
    } else {
      if (mf > 1.5f) { xx = 1.0f - xx; yy = 1.0f - yy; }
      float lin = w0 * xx + w1 * yy;
      float g   = exp2f(e0 * log2f(xx) + e1 * log2f(yy));
      r = cl * lin + cg * g;
      if (mf > 1.5f) r = 1.0f - r;
    }
    st = (r != r) ? av : r;   // NaN fallback to bias
  }
  out[b] = st;
}

// ---------------------------------------------------------------------------
extern "C" void kernel_launch(void* const* d_in, const int* in_sizes, int n_in,
                              void* d_out, int out_size, void* d_ws, size_t ws_size,
                              hipStream_t stream) {
  const float* x       = (const float*)d_in[0];
  const float* logits  = (const float*)d_in[1];
  const float* weights = (const float*)d_in[2];
  const float* biases  = (const float*)d_in[3];
  float* out = (float*)d_out;

  float* P      = (float*)d_ws;                                 // 16 KB
  float* layers = (float*)((char*)d_ws + N * N * sizeof(float)); // 63*8 floats

  const int batch = out_size;  // 262144

  hipLaunchKernelGGL(sinkhorn_kernel, dim3(1), dim3(64), 0, stream,
                     logits, weights, biases, P, layers);
  hipLaunchKernelGGL(scan_kernel, dim3(batch / 256), dim3(256), 0, stream,
                     x, P, layers, out);
}

// Round 6
// 150.021 us; speedup vs baseline: 1.1433x; 1.0156x over previous
//
#include <hip/hip_runtime.h>
#include <math.h>

#define EPS 1e-6f
#define N 64          // INPUT_SIZE == NUM_LEAVES
#define NLAYERS 63
#define SINK_ITERS 20
#define LOG2E 1.4426950408889634f

typedef __attribute__((ext_vector_type(8))) short bf16x8;   // 8 bf16 = 4 VGPRs
typedef __attribute__((ext_vector_type(4))) float f32x4;    // MFMA C/D

// fp32 -> bf16, round-to-nearest-even (bit pattern in ushort)
__device__ __forceinline__ unsigned short f2bf(float f) {
  unsigned int u = __float_as_uint(f);
  return (unsigned short)((u + 0x7FFFu + ((u >> 16) & 1u)) >> 16);
}

// ---------------------------------------------------------------------------
// Kernel 1: Sinkhorn (scaling-vector form, single wave) + P -> MFMA B-fragment
// precompute (bf16) + per-layer scan constants.
// P = diag(u) K diag(v), K = exp(logits); u = 1/(K v), v = 1/(K^T u).
// B-frag layout for mfma_f32_16x16x32_bf16: lane l holds
// B[k = s*32 + (l>>4)*8 + j][n = t*16 + (l&15)], j=0..7, for K-step s, N-tile t.
// Pfrag[((s*4+t)*64 + l)*8 + j] -> each lane's frag is 16 contiguous bytes.
// ---------------------------------------------------------------------------
__global__ __launch_bounds__(64) void sinkhorn_kernel(
    const float* __restrict__ logits,
    const float* __restrict__ weights,
    const float* __restrict__ biases,
    unsigned short* __restrict__ Pfrag,  // [8][64][8] bf16
    float* __restrict__ layers) {        // [63][8]: w0,w1,e0,e1,cl,cg,a,mode
  __shared__ float T[64 * 65 + 128];
  const int l = threadIdx.x;

  float K[64];
  {
    const float4* lr = (const float4*)(logits + (l << 6));
    #pragma unroll
    for (int q = 0; q < 16; ++q) {
      float4 t = lr[q];
      K[4*q+0] = exp2f(t.x * LOG2E);
      K[4*q+1] = exp2f(t.y * LOG2E);
      K[4*q+2] = exp2f(t.z * LOG2E);
      K[4*q+3] = exp2f(t.w * LOG2E);
    }
  }
  #pragma unroll
  for (int j = 0; j < 64; ++j) T[l * 65 + j] = K[j];
  __syncthreads();
  float KT[64];
  #pragma unroll
  for (int k = 0; k < 64; ++k) KT[k] = T[k * 65 + l];
  __syncthreads();

  float* Uv = &T[64 * 65];
  float* Vv = &T[64 * 65 + 64];
  Vv[l] = 1.0f;
  __syncthreads();

  float u = 1.0f;
  for (int it = 0; it < SINK_ITERS; ++it) {
    float r = 0.f;
    #pragma unroll
    for (int j = 0; j < 64; ++j) r = fmaf(K[j], Vv[j], r);
    u = 1.0f / r;
    __syncthreads();
    Uv[l] = u;
    __syncthreads();
    float c = 0.f;
    #pragma unroll
    for (int k = 0; k < 64; ++k) c = fmaf(KT[k], Uv[k], c);
    float v = 1.0f / c;
    __syncthreads();
    Vv[l] = v;
    __syncthreads();
  }

  // P row l into LDS (K-transpose area is dead; Vv area untouched).
  #pragma unroll
  for (int j = 0; j < 64; ++j) T[l * 65 + j] = u * K[j] * Vv[j];
  __syncthreads();

  // Gather B fragments.
  #pragma unroll
  for (int s = 0; s < 2; ++s)
    #pragma unroll
    for (int t = 0; t < 4; ++t) {
      unsigned short buf[8];
      #pragma unroll
      for (int j = 0; j < 8; ++j)
        buf[j] = f2bf(T[(s*32 + ((l >> 4) << 3) + j) * 65 + t*16 + (l & 15)]);
      *(bf16x8*)(Pfrag + (((s*4 + t) * 64 + l) << 3)) = *(bf16x8*)buf;
    }

  // Per-layer scan constants (a = bias in [0,1): |a-2|<eps never fires).
  if (l < NLAYERS) {
    float w0 = weights[l];
    float w1 = 1.0f - w0;
    float a  = biases[l];
    float e0 = 0.f, e1 = 0.f, cl = 0.f, cg = 0.f, mode;
    if (fabsf(a - 0.5f) < EPS) {
      mode = 0.0f;
    } else {
      float ae;
      if (a < 0.5f) { mode = 2.0f; ae = fminf(fmaxf(1.0f - a, -1.0f + EPS), 2.0f - EPS); }
      else          { mode = 1.0f; ae = a; }
      float pp = sqrtf(3.0f / fmaxf(2.0f - ae, EPS)) - 1.0f;
      if (ae >= 0.75f) { cl = 0.0f;            cg = 1.0f; }
      else             { cl = 3.0f - 4.0f*ae;  cg = 4.0f*ae - 2.0f; }
      e0 = 2.0f * w0 * pp;
      e1 = 2.0f * w1 * pp;
    }
    float* Lr = layers + l * 8;
    Lr[0] = w0; Lr[1] = w1; Lr[2] = e0; Lr[3] = e1;
    Lr[4] = cl; Lr[5] = cg; Lr[6] = a;  Lr[7] = mode;
  }
}

// ---------------------------------------------------------------------------
// Kernel 2: MFMA GEMM (x @ P -> leaves) + tree scan.
// Block = 256 thr (4 waves) = 64 batch rows. Wave w computes rows w*16..+15
// with 8x mfma_f32_16x16x32_bf16 (A layout: A[m=lane&15][k=quad*8+j];
// C/D: col=lane&15, row=quad*4+reg -- m89-verified mappings).
// D -> LDS (stride 65, conflict-free column reads) -> wave 0 scans 64 rows.
// ---------------------------------------------------------------------------
__global__ __launch_bounds__(256) void scan_kernel(
    const float* __restrict__ x,
    const unsigned short* __restrict__ Pfrag,
    const float* __restrict__ layers,
    float* __restrict__ out) {
  __shared__ unsigned short As[64 * 72];  // bf16 x-tile, row stride 72 (144 B)
  __shared__ float Lv[64 * 65];           // leaves, row stride 65
  const int tid = threadIdx.x;
  const int w = tid >> 6, l = tid & 63;
  const size_t rowbase = (size_t)blockIdx.x << 6;

  // ---- stage: 64x64 fp32 -> bf16 LDS. thread t: row t>>2, col-quarter t&3.
  {
    const int r = tid >> 2, c = tid & 3;
    const float4* xp = (const float4*)(x + (rowbase + r) * 64 + c * 16);
    unsigned short buf[16];
    #pragma unroll
    for (int q = 0; q < 4; ++q) {
      float4 v = xp[q];
      buf[4*q+0] = f2bf(v.x); buf[4*q+1] = f2bf(v.y);
      buf[4*q+2] = f2bf(v.z); buf[4*q+3] = f2bf(v.w);
    }
    *(bf16x8*)&As[r * 72 + c * 16]     = *(bf16x8*)&buf[0];
    *(bf16x8*)&As[r * 72 + c * 16 + 8] = *(bf16x8*)&buf[8];
  }

  // ---- B fragments (same for all waves; 8 KB, L2-hot after first blocks).
  bf16x8 B[2][4];
  #pragma unroll
  for (int s = 0; s < 2; ++s)
    #pragma unroll
    for (int t = 0; t < 4; ++t)
      B[s][t] = *(const bf16x8*)(Pfrag + (((s*4 + t) * 64 + l) << 3));

  __syncthreads();

  // ---- A fragments + MFMA + D scatter to LDS.
  const int am = (w << 4) + (l & 15);      // A row (m)
  const int aq = (l >> 4) << 3;            // k offset within K-step
  bf16x8 A0 = *(bf16x8*)&As[am * 72 +      aq];
  bf16x8 A1 = *(bf16x8*)&As[am * 72 + 32 + aq];

  #pragma unroll
  for (int t = 0; t < 4; ++t) {
    f32x4 acc = {0.f, 0.f, 0.f, 0.f};
    acc = __builtin_amdgcn_mfma_f32_16x16x32_bf16(A0, B[0][t], acc, 0, 0, 0);
    acc = __builtin_amdgcn_mfma_f32_16x16x32_bf16(A1, B[1][t], acc, 0, 0, 0);
    const int drow = (w << 4) + ((l >> 4) << 2);
    const int dcol = (t << 4) + (l & 15);
    #pragma unroll
    for (int reg = 0; reg < 4; ++reg)
      Lv[(drow + reg) * 65 + dcol] = acc[reg];
  }

  __syncthreads();

  // ---- wave 0: serial scan per batch row (column reads conflict-free).
  if (tid < 64) {
    float st = Lv[tid * 65];
    #pragma unroll 1
    for (int j = 1; j < N; ++j) {
      const float* Lr = layers + (j - 1) * 8;   // uniform -> scalar loads
      float w0 = Lr[0], w1 = Lr[1], e0 = Lr[2], e1 = Lr[3];
      float cl = Lr[4], cg = Lr[5], av = Lr[6], mf = Lr[7];
      float xx = fminf(fmaxf(st,            EPS), 1.0f - EPS);
      float yy = fminf(fmaxf(Lv[tid*65 + j], EPS), 1.0f - EPS);
      float r;
      if (mf < 0.5f) {
        r = w0 * xx + w1 * yy;
      } else {
        if (mf > 1.5f) { xx = 1.0f - xx; yy = 1.0f - yy; }
        float lin = w0 * xx + w1 * yy;
        float g   = exp2f(e0 * log2f(xx) + e1 * log2f(yy));
        r = cl * lin + cg * g;
        if (mf > 1.5f) r = 1.0f - r;
      }
      st = (r != r) ? av : r;   // NaN fallback to bias
    }
    out[rowbase + tid] = st;
  }
}

// ---------------------------------------------------------------------------
extern "C" void kernel_launch(void* const* d_in, const int* in_sizes, int n_in,
                              void* d_out, int out_size, void* d_ws, size_t ws_size,
                              hipStream_t stream) {
  const float* x       = (const float*)d_in[0];
  const float* logits  = (const float*)d_in[1];
  const float* weights = (const float*)d_in[2];
  const float* biases  = (const float*)d_in[3];
  float* out = (float*)d_out;

  unsigned short* Pfrag = (unsigned short*)d_ws;              // 8 KB
  float* layers = (float*)((char*)d_ws + 8 * 64 * 8 * sizeof(unsigned short));

  const int batch = out_size;  // 262144

  hipLaunchKernelGGL(sinkhorn_kernel, dim3(1), dim3(64), 0, stream,
                     logits, weights, biases, Pfrag, layers);
  hipLaunchKernelGGL(scan_kernel, dim3(batch / 64), dim3(256), 0, stream,
                     x, Pfrag, layers, out);
}

// Round 8
// 133.586 us; speedup vs baseline: 1.2840x; 1.1230x over previous
//
#include <hip/hip_runtime.h>
#include <hip/hip_bf16.h>
#include <math.h>

#define EPS 1e-6f
#define N 64          // INPUT_SIZE == NUM_LEAVES
#define NLAYERS 63
#define SINK_ITERS 20
#define LOG2E 1.4426950408889634f

typedef __attribute__((ext_vector_type(8))) short bf16x8;   // 8 bf16 = 4 VGPRs
typedef __attribute__((ext_vector_type(4))) float f32x4;    // MFMA C/D

// fp32 -> bf16 round-to-nearest-even (bit pattern in ushort)
__device__ __forceinline__ unsigned short f2bf(float f) {
  unsigned int u = __float_as_uint(f);
  return (unsigned short)((u + 0x7FFFu + ((u >> 16) & 1u)) >> 16);
}

// ---------------------------------------------------------------------------
// Kernel 1: Sinkhorn (scaling-vector form, single wave) + P -> MFMA B-fragment
// precompute (bf16) + per-layer scan constants. (Validated in R6 - unchanged.)
// B-frag for mfma_f32_16x16x32_bf16: lane l holds
// B[k = s*32 + (l>>4)*8 + j][n = t*16 + (l&15)], j=0..7.
// ---------------------------------------------------------------------------
__global__ __launch_bounds__(64) void sinkhorn_kernel(
    const float* __restrict__ logits,
    const float* __restrict__ weights,
    const float* __restrict__ biases,
    unsigned short* __restrict__ Pfrag,  // [8][64][8] bf16
    float* __restrict__ layers) {        // [63][8]: w0,w1,e0,e1,cl,cg,a,mode
  __shared__ float T[64 * 65 + 128];
  const int l = threadIdx.x;

  float K[64];
  {
    const float4* lr = (const float4*)(logits + (l << 6));
    #pragma unroll
    for (int q = 0; q < 16; ++q) {
      float4 t = lr[q];
      K[4*q+0] = exp2f(t.x * LOG2E);
      K[4*q+1] = exp2f(t.y * LOG2E);
      K[4*q+2] = exp2f(t.z * LOG2E);
      K[4*q+3] = exp2f(t.w * LOG2E);
    }
  }
  #pragma unroll
  for (int j = 0; j < 64; ++j) T[l * 65 + j] = K[j];
  __syncthreads();
  float KT[64];
  #pragma unroll
  for (int k = 0; k < 64; ++k) KT[k] = T[k * 65 + l];
  __syncthreads();

  float* Uv = &T[64 * 65];
  float* Vv = &T[64 * 65 + 64];
  Vv[l] = 1.0f;
  __syncthreads();

  float u = 1.0f;
  for (int it = 0; it < SINK_ITERS; ++it) {
    float r = 0.f;
    #pragma unroll
    for (int j = 0; j < 64; ++j) r = fmaf(K[j], Vv[j], r);
    u = 1.0f / r;
    __syncthreads();
    Uv[l] = u;
    __syncthreads();
    float c = 0.f;
    #pragma unroll
    for (int k = 0; k < 64; ++k) c = fmaf(KT[k], Uv[k], c);
    float v = 1.0f / c;
    __syncthreads();
    Vv[l] = v;
    __syncthreads();
  }

  #pragma unroll
  for (int j = 0; j < 64; ++j) T[l * 65 + j] = u * K[j] * Vv[j];
  __syncthreads();

  #pragma unroll
  for (int s = 0; s < 2; ++s)
    #pragma unroll
    for (int t = 0; t < 4; ++t) {
      unsigned short buf[8];
      #pragma unroll
      for (int j = 0; j < 8; ++j)
        buf[j] = f2bf(T[(s*32 + ((l >> 4) << 3) + j) * 65 + t*16 + (l & 15)]);
      *(bf16x8*)(Pfrag + (((s*4 + t) * 64 + l) << 3)) = *(bf16x8*)buf;
    }

  if (l < NLAYERS) {
    float w0 = weights[l];
    float w1 = 1.0f - w0;
    float a  = biases[l];
    float e0 = 0.f, e1 = 0.f, cl = 0.f, cg = 0.f, mode;
    if (fabsf(a - 0.5f) < EPS) {
      mode = 0.0f;
    } else {
      float ae;
      if (a < 0.5f) { mode = 2.0f; ae = fminf(fmaxf(1.0f - a, -1.0f + EPS), 2.0f - EPS); }
      else          { mode = 1.0f; ae = a; }
      float pp = sqrtf(3.0f / fmaxf(2.0f - ae, EPS)) - 1.0f;
      if (ae >= 0.75f) { cl = 0.0f;            cg = 1.0f; }
      else             { cl = 3.0f - 4.0f*ae;  cg = 4.0f*ae - 2.0f; }
      e0 = 2.0f * w0 * pp;
      e1 = 2.0f * w1 * pp;
    }
    float* Lr = layers + l * 8;
    Lr[0] = w0; Lr[1] = w1; Lr[2] = e0; Lr[3] = e1;
    Lr[4] = cl; Lr[5] = cg; Lr[6] = a;  Lr[7] = mode;
  }
}

// ---------------------------------------------------------------------------
// F step (wave-uniform branch; Lp is a uniform address -> scalar loads).
// ---------------------------------------------------------------------------
__device__ __forceinline__ float F_step(float st, float leaf,
                                        const float* __restrict__ Lp) {
  float w0 = Lp[0], w1 = Lp[1], e0 = Lp[2], e1 = Lp[3];
  float cl = Lp[4], cg = Lp[5], av = Lp[6], mf = Lp[7];
  float xx = fminf(fmaxf(st,   EPS), 1.0f - EPS);
  float yy = fminf(fmaxf(leaf, EPS), 1.0f - EPS);
  float r;
  if (mf < 0.5f) {
    r = w0 * xx + w1 * yy;
  } else {
    if (mf > 1.5f) { xx = 1.0f - xx; yy = 1.0f - yy; }
    float lin = w0 * xx + w1 * yy;
    float g   = exp2f(e0 * log2f(xx) + e1 * log2f(yy));
    r = cl * lin + cg * g;
    if (mf > 1.5f) r = 1.0f - r;
  }
  return (r != r) ? av : r;   // NaN fallback to bias
}

// ---------------------------------------------------------------------------
// Kernel 2: 256 rows/block, 256 threads. One 36.9 KB LDS region, two views:
//   Xs: bf16 x-tile [256][72]   (36864 B)  -- dead after A-frag preload
//   Lv: fp32 leaves [256][33]   (33792 B)  -- overlays Xs
// Phases: stage x -> sync -> A-preload (regs) -> sync ->
//         GEMM n-cols 0..31 -> sync -> scan steps 0..31 (own row) -> sync ->
//         GEMM n-cols 32..63 -> sync -> scan steps 32..63 -> store.
// fp32 leaves => absmax stays at R6's level. All 256 threads scan.
// ---------------------------------------------------------------------------
__global__ __launch_bounds__(256, 4) void scan_kernel(
    const float* __restrict__ x,
    const unsigned short* __restrict__ Pfrag,
    const float* __restrict__ layers,
    float* __restrict__ out) {
  __shared__ __align__(16) unsigned char SM[256 * 72 * 2];
  unsigned short* Xs = (unsigned short*)SM;   // stride 72 shorts
  float* Lv = (float*)SM;                     // stride 33 floats
  const int tid = threadIdx.x;
  const int w = tid >> 6, l = tid & 63;
  const size_t rowbase = (size_t)blockIdx.x << 8;   // 256 rows per block

  // B fragments (global, 8 KB, L2-hot; wave-uniform addresses)
  bf16x8 B[2][4];
  #pragma unroll
  for (int s = 0; s < 2; ++s)
    #pragma unroll
    for (int t = 0; t < 4; ++t)
      B[s][t] = *(const bf16x8*)(Pfrag + (((s*4 + t) * 64 + l) << 3));

  // ---- stage 256x64 fp32 -> bf16 LDS: 4096 float4s, 16 per thread.
  {
    const float4* xp = (const float4*)(x + (rowbase << 6));
    #pragma unroll
    for (int c = 0; c < 16; ++c) {
      int idx = (c << 8) + tid;            // 0..4095, coalesced
      float4 v = xp[idx];
      union { unsigned short us[4]; uint2 u2; } pk;
      pk.us[0] = f2bf(v.x); pk.us[1] = f2bf(v.y);
      pk.us[2] = f2bf(v.z); pk.us[3] = f2bf(v.w);
      int row = idx >> 4, cs = (idx & 15) << 2;
      *(uint2*)&Xs[row * 72 + cs] = pk.u2;  // byte ofs row*144 + 8k: 8B-aligned
    }
  }
  __syncthreads();

  // ---- A-fragment preload: wave w owns rows w*64..+63 (4 m-tiles).
  bf16x8 A[4][2];
  #pragma unroll
  for (int i = 0; i < 4; ++i)
    #pragma unroll
    for (int s = 0; s < 2; ++s)
      A[i][s] = *(bf16x8*)&Xs[(((w << 2) + i) * 16 + (l & 15)) * 72
                              + (s << 5) + ((l >> 4) << 3)];
  __syncthreads();   // ALL waves done reading Xs before Lv overwrites it

  float st;
  #pragma unroll
  for (int half = 0; half < 2; ++half) {
    // ---- GEMM: n-cols half*32 .. half*32+31 -> fp32 leaves in Lv
    #pragma unroll
    for (int i = 0; i < 4; ++i) {
      const int drow0 = ((w << 2) + i) * 16 + ((l >> 4) << 2);
      #pragma unroll
      for (int tn = 0; tn < 2; ++tn) {
        const int t = (half << 1) + tn;    // global n-tile
        f32x4 acc = {0.f, 0.f, 0.f, 0.f};
        acc = __builtin_amdgcn_mfma_f32_16x16x32_bf16(A[i][0], B[0][t], acc, 0, 0, 0);
        acc = __builtin_amdgcn_mfma_f32_16x16x32_bf16(A[i][1], B[1][t], acc, 0, 0, 0);
        const int dcol = (tn << 4) + (l & 15);   // local col 0..31
        #pragma unroll
        for (int r = 0; r < 4; ++r)
          Lv[(drow0 + r) * 33 + dcol] = acc[r];
      }
    }
    __syncthreads();

    // ---- scan: thread tid processes its own row (stride 33 -> 2-way = free)
    if (half == 0) {
      st = Lv[tid * 33];                   // leaf 0 (fp32)
      #pragma unroll
      for (int j = 1; j < 32; ++j)
        st = F_step(st, Lv[tid * 33 + j], layers + (j - 1) * 8);
    } else {
      #pragma unroll
      for (int j = 32; j < 64; ++j)
        st = F_step(st, Lv[tid * 33 + (j - 32)], layers + (j - 1) * 8);
    }
    __syncthreads();   // half 0: reads done before half 1 overwrites Lv
  }

  out[rowbase + tid] = st;
}

// ---------------------------------------------------------------------------
extern "C" void kernel_launch(void* const* d_in, const int* in_sizes, int n_in,
                              void* d_out, int out_size, void* d_ws, size_t ws_size,
                              hipStream_t stream) {
  const float* x       = (const float*)d_in[0];
  const float* logits  = (const float*)d_in[1];
  const float* weights = (const float*)d_in[2];
  const float* biases  = (const float*)d_in[3];
  float* out = (float*)d_out;

  unsigned short* Pfrag = (unsigned short*)d_ws;              // 8 KB
  float* layers = (float*)((char*)d_ws + 8 * 64 * 8 * sizeof(unsigned short));

  const int batch = out_size;  // 262144

  hipLaunchKernelGGL(sinkhorn_kernel, dim3(1), dim3(64), 0, stream,
                     logits, weights, biases, Pfrag, layers);
  hipLaunchKernelGGL(scan_kernel, dim3(batch / 256), dim3(256), 0, stream,
                     x, Pfrag, layers, out);
}

// Round 9
// 132.297 us; speedup vs baseline: 1.2965x; 1.0097x over previous
//
#include <hip/hip_runtime.h>
#include <hip/hip_bf16.h>
#include <math.h>

#define EPS 1e-6f
#define N 64          // INPUT_SIZE == NUM_LEAVES
#define NLAYERS 63
#define SINK_ITERS 20
#define LOG2E 1.4426950408889634f

typedef __attribute__((ext_vector_type(8))) short bf16x8;   // 8 bf16 = 4 VGPRs
typedef __attribute__((ext_vector_type(4))) float f32x4;    // MFMA C/D

// fp32 -> bf16 round-to-nearest-even (bit pattern in ushort)
__device__ __forceinline__ unsigned short f2bf(float f) {
  unsigned int u = __float_as_uint(f);
  return (unsigned short)((u + 0x7FFFu + ((u >> 16) & 1u)) >> 16);
}

// ---------------------------------------------------------------------------
// Kernel 1: Sinkhorn (scaling-vector form, single wave) + P -> MFMA B-fragment
// precompute (bf16) + per-layer scan constants.
// R9: dot products use 4 independent accumulators (dependent-chain 256->64
// cyc) and Vv/Uv are read as float4 broadcasts (ds_read_b128, 16 issues/pass).
// B-frag for mfma_f32_16x16x32_bf16: lane l holds
// B[k = s*32 + (l>>4)*8 + j][n = t*16 + (l&15)], j=0..7.
// ---------------------------------------------------------------------------
__global__ __launch_bounds__(64) void sinkhorn_kernel(
    const float* __restrict__ logits,
    const float* __restrict__ weights,
    const float* __restrict__ biases,
    unsigned short* __restrict__ Pfrag,  // [8][64][8] bf16
    float* __restrict__ layers) {        // [63][8]: w0,w1,e0,e1,cl,cg,a,mode
  __shared__ float T[64 * 65 + 128];     // transpose area + u/v slots (16B-aligned)
  const int l = threadIdx.x;

  float K[64];
  {
    const float4* lr = (const float4*)(logits + (l << 6));
    #pragma unroll
    for (int q = 0; q < 16; ++q) {
      float4 t = lr[q];
      K[4*q+0] = exp2f(t.x * LOG2E);
      K[4*q+1] = exp2f(t.y * LOG2E);
      K[4*q+2] = exp2f(t.z * LOG2E);
      K[4*q+3] = exp2f(t.w * LOG2E);
    }
  }
  #pragma unroll
  for (int j = 0; j < 64; ++j) T[l * 65 + j] = K[j];
  __syncthreads();
  float KT[64];
  #pragma unroll
  for (int k = 0; k < 64; ++k) KT[k] = T[k * 65 + l];
  __syncthreads();

  float* Uv = &T[64 * 65];        // byte offset 16640: 16B-aligned
  float* Vv = &T[64 * 65 + 64];   // +256 B: 16B-aligned
  const float4* Uv4 = (const float4*)Uv;
  const float4* Vv4 = (const float4*)Vv;
  Vv[l] = 1.0f;
  __syncthreads();

  float u = 1.0f;
  for (int it = 0; it < SINK_ITERS; ++it) {
    // row pass: u = 1 / (K v) -- 4 chains + float4 broadcast reads
    float s0 = 0.f, s1 = 0.f, s2 = 0.f, s3 = 0.f;
    #pragma unroll
    for (int q = 0; q < 16; ++q) {
      float4 v = Vv4[q];
      s0 = fmaf(K[4*q+0], v.x, s0);
      s1 = fmaf(K[4*q+1], v.y, s1);
      s2 = fmaf(K[4*q+2], v.z, s2);
      s3 = fmaf(K[4*q+3], v.w, s3);
    }
    u = 1.0f / ((s0 + s1) + (s2 + s3));
    __syncthreads();
    Uv[l] = u;
    __syncthreads();
    // col pass: v = 1 / (K^T u)
    float c0 = 0.f, c1 = 0.f, c2 = 0.f, c3 = 0.f;
    #pragma unroll
    for (int q = 0; q < 16; ++q) {
      float4 uu = Uv4[q];
      c0 = fmaf(KT[4*q+0], uu.x, c0);
      c1 = fmaf(KT[4*q+1], uu.y, c1);
      c2 = fmaf(KT[4*q+2], uu.z, c2);
      c3 = fmaf(KT[4*q+3], uu.w, c3);
    }
    float v = 1.0f / ((c0 + c1) + (c2 + c3));
    __syncthreads();
    Vv[l] = v;
    __syncthreads();
  }

  #pragma unroll
  for (int j = 0; j < 64; ++j) T[l * 65 + j] = u * K[j] * Vv[j];
  __syncthreads();

  #pragma unroll
  for (int s = 0; s < 2; ++s)
    #pragma unroll
    for (int t = 0; t < 4; ++t) {
      union { unsigned short us[8]; bf16x8 v; } buf;
      #pragma unroll
      for (int j = 0; j < 8; ++j)
        buf.us[j] = f2bf(T[(s*32 + ((l >> 4) << 3) + j) * 65 + t*16 + (l & 15)]);
      *(bf16x8*)(Pfrag + (((s*4 + t) * 64 + l) << 3)) = buf.v;
    }

  if (l < NLAYERS) {
    float w0 = weights[l];
    float w1 = 1.0f - w0;
    float a  = biases[l];
    float e0 = 0.f, e1 = 0.f, cl = 0.f, cg = 0.f, mode;
    if (fabsf(a - 0.5f) < EPS) {
      mode = 0.0f;
    } else {
      float ae;
      if (a < 0.5f) { mode = 2.0f; ae = fminf(fmaxf(1.0f - a, -1.0f + EPS), 2.0f - EPS); }
      else          { mode = 1.0f; ae = a; }
      float pp = sqrtf(3.0f / fmaxf(2.0f - ae, EPS)) - 1.0f;
      if (ae >= 0.75f) { cl = 0.0f;            cg = 1.0f; }
      else             { cl = 3.0f - 4.0f*ae;  cg = 4.0f*ae - 2.0f; }
      e0 = 2.0f * w0 * pp;
      e1 = 2.0f * w1 * pp;
    }
    float* Lr = layers + l * 8;
    Lr[0] = w0; Lr[1] = w1; Lr[2] = e0; Lr[3] = e1;
    Lr[4] = cl; Lr[5] = cg; Lr[6] = a;  Lr[7] = mode;
  }
}

// ---------------------------------------------------------------------------
// F step (wave-uniform branch; Lp is a uniform address -> scalar loads).
// ---------------------------------------------------------------------------
__device__ __forceinline__ float F_step(float st, float leaf,
                                        const float* __restrict__ Lp) {
  float w0 = Lp[0], w1 = Lp[1], e0 = Lp[2], e1 = Lp[3];
  float cl = Lp[4], cg = Lp[5], av = Lp[6], mf = Lp[7];
  float xx = fminf(fmaxf(st,   EPS), 1.0f - EPS);
  float yy = fminf(fmaxf(leaf, EPS), 1.0f - EPS);
  float r;
  if (mf < 0.5f) {
    r = w0 * xx + w1 * yy;
  } else {
    if (mf > 1.5f) { xx = 1.0f - xx; yy = 1.0f - yy; }
    float lin = w0 * xx + w1 * yy;
    float g   = exp2f(e0 * log2f(xx) + e1 * log2f(yy));
    r = cl * lin + cg * g;
    if (mf > 1.5f) r = 1.0f - r;
  }
  return (r != r) ? av : r;   // NaN fallback to bias
}

// ---------------------------------------------------------------------------
// Kernel 2 (R9): 256 rows/block, ZERO BARRIERS.
// All dependences are wave-local: wave w's MFMAs produce D rows w*64..+63,
// and thread tid scans row tid (same wave). Same-wave LDS write->read is
// ordered by the DS pipe + compiler lgkmcnt -- no __syncthreads anywhere.
//   - A-fragments gathered DIRECTLY from global (fp32->bf16 cvt in regs):
//     frag(i,s): row = rowbase + w*64 + i*16 + (l&15), cols s*32+(l>>4)*8..+7
//   - LDS = fp32 leaf buffer [256][33] only (33792 B -> 4 blocks/CU)
//   - n-halves: GEMM(cols 0..31) -> scan steps 1..31 -> GEMM(32..63) -> scan.
// ---------------------------------------------------------------------------
__global__ __launch_bounds__(256, 4) void scan_kernel(
    const float* __restrict__ x,
    const unsigned short* __restrict__ Pfrag,
    const float* __restrict__ layers,
    float* __restrict__ out) {
  __shared__ float Lv[256 * 33];   // stride 33: bank = (row+col)%32, 2-way free
  const int tid = threadIdx.x;
  const int w = tid >> 6, l = tid & 63;
  const size_t rowbase = (size_t)blockIdx.x << 8;   // 256 rows per block

  // ---- A fragments: direct global gather (cold -> issue first).
  float4 araw[4][2][2];
  #pragma unroll
  for (int i = 0; i < 4; ++i) {
    const float* rp = x + (rowbase + (w << 6) + (i << 4) + (l & 15)) * 64
                        + ((l >> 4) << 3);
    #pragma unroll
    for (int s = 0; s < 2; ++s) {
      araw[i][s][0] = *(const float4*)(rp + (s << 5));
      araw[i][s][1] = *(const float4*)(rp + (s << 5) + 4);
    }
  }

  // ---- B fragments (global, 8 KB, L2/L3-hot).
  bf16x8 B[2][4];
  #pragma unroll
  for (int s = 0; s < 2; ++s)
    #pragma unroll
    for (int t = 0; t < 4; ++t)
      B[s][t] = *(const bf16x8*)(Pfrag + (((s*4 + t) * 64 + l) << 3));

  // ---- cvt A to bf16 fragments.
  bf16x8 A[4][2];
  #pragma unroll
  for (int i = 0; i < 4; ++i)
    #pragma unroll
    for (int s = 0; s < 2; ++s) {
      union { unsigned short us[8]; bf16x8 v; } buf;
      float4 v0 = araw[i][s][0], v1 = araw[i][s][1];
      buf.us[0] = f2bf(v0.x); buf.us[1] = f2bf(v0.y);
      buf.us[2] = f2bf(v0.z); buf.us[3] = f2bf(v0.w);
      buf.us[4] = f2bf(v1.x); buf.us[5] = f2bf(v1.y);
      buf.us[6] = f2bf(v1.z); buf.us[7] = f2bf(v1.w);
      A[i][s] = buf.v;
    }

  float st = 0.f;
  #pragma unroll
  for (int half = 0; half < 2; ++half) {
    // ---- GEMM: n-cols half*32 .. half*32+31 -> fp32 leaves (own wave rows).
    #pragma unroll
    for (int i = 0; i < 4; ++i) {
      const int drow0 = (w << 6) + (i << 4) + ((l >> 4) << 2);
      #pragma unroll
      for (int tn = 0; tn < 2; ++tn) {
        const int t = (half << 1) + tn;    // global n-tile
        f32x4 acc = {0.f, 0.f, 0.f, 0.f};
        acc = __builtin_amdgcn_mfma_f32_16x16x32_bf16(A[i][0], B[0][t], acc, 0, 0, 0);
        acc = __builtin_amdgcn_mfma_f32_16x16x32_bf16(A[i][1], B[1][t], acc, 0, 0, 0);
        const int dcol = (tn << 4) + (l & 15);   // local col 0..31
        #pragma unroll
        for (int r = 0; r < 4; ++r)
          Lv[(drow0 + r) * 33 + dcol] = acc[r];
      }
    }
    // Same-wave producer/consumer: DS-pipe ordering + lgkmcnt, no barrier.
    if (half == 0) {
      st = Lv[tid * 33];                   // leaf 0 (fp32)
      #pragma unroll
      for (int j = 1; j < 32; ++j)
        st = F_step(st, Lv[tid * 33 + j], layers + (j - 1) * 8);
    } else {
      #pragma unroll
      for (int j = 32; j < 64; ++j)
        st = F_step(st, Lv[tid * 33 + (j - 32)], layers + (j - 1) * 8);
    }
  }

  out[rowbase + tid] = st;
}

// ---------------------------------------------------------------------------
extern "C" void kernel_launch(void* const* d_in, const int* in_sizes, int n_in,
                              void* d_out, int out_size, void* d_ws, size_t ws_size,
                              hipStream_t stream) {
  const float* x       = (const float*)d_in[0];
  const float* logits  = (const float*)d_in[1];
  const float* weights = (const float*)d_in[2];
  const float* biases  = (const float*)d_in[3];
  float* out = (float*)d_out;

  unsigned short* Pfrag = (unsigned short*)d_ws;              // 8 KB
  float* layers = (float*)((char*)d_ws + 8 * 64 * 8 * sizeof(unsigned short));

  const int batch = out_size;  // 262144

  hipLaunchKernelGGL(sinkhorn_kernel, dim3(1), dim3(64), 0, stream,
                     logits, weights, biases, Pfrag, layers);
  hipLaunchKernelGGL(scan_kernel, dim3(batch / 256), dim3(256), 0, stream,
                     x, Pfrag, layers, out);
}